// Round 1
// baseline (1592.110 us; speedup 1.0000x reference)
//
#include <hip/hip_runtime.h>

#define N_NODES 100000
#define HID 64

// ---------------------------------------------------------------- degree
__global__ __launch_bounds__(256) void count_deg(const int* __restrict__ dst,
                                                 int* __restrict__ deg, int E) {
  int i = blockIdx.x * 256 + threadIdx.x;
  const int stride = gridDim.x * 256;
  for (; i < E; i += stride) atomicAdd(&deg[dst[i]], 1);
}

__global__ __launch_bounds__(256) void compute_dinv(const int* __restrict__ deg,
                                                    float* __restrict__ dinv, int n) {
  const int i = blockIdx.x * 256 + threadIdx.x;
  if (i < n) dinv[i] = rsqrtf((float)(deg[i] + 1));  // +1 self-loop
}

// ---------------------------------------------------------------- dense transform
// out[i, c] = dinv[i] * sum_k x[i,k] * W[k,c]      (16 rows/block, 64 cols, K=128 or 64)
template <int K>
__global__ __launch_bounds__(256) void gemm_nodes(const float* __restrict__ x,
                                                  const float* __restrict__ W,
                                                  const float* __restrict__ dinv,
                                                  float* __restrict__ out) {
  __shared__ float Wl[K * 64];
  __shared__ float xl[16][K];
  const int tid = threadIdx.x;
  for (int i = tid; i < K * 16; i += 256)  // K*64/4 float4s
    reinterpret_cast<float4*>(Wl)[i] = reinterpret_cast<const float4*>(W)[i];
  const int row0 = blockIdx.x * 16;
  for (int i = tid; i < 16 * (K / 4); i += 256) {
    const int r = i / (K / 4), q = i % (K / 4);
    reinterpret_cast<float4*>(&xl[r][0])[q] =
        reinterpret_cast<const float4*>(x + (size_t)(row0 + r) * K)[q];
  }
  __syncthreads();
  const int c = tid & 63;     // output col  (lanes consecutive -> conflict-free W reads)
  const int rbase = tid >> 6; // wave's starting row
  for (int rr = rbase; rr < 16; rr += 4) {
    float acc = 0.f;
#pragma unroll
    for (int k = 0; k < K; k += 4) {
      const float4 xv = *reinterpret_cast<const float4*>(&xl[rr][k]);  // broadcast
      acc = fmaf(xv.x, Wl[(k + 0) * 64 + c], acc);
      acc = fmaf(xv.y, Wl[(k + 1) * 64 + c], acc);
      acc = fmaf(xv.z, Wl[(k + 2) * 64 + c], acc);
      acc = fmaf(xv.w, Wl[(k + 3) * 64 + c], acc);
    }
    const int grow = row0 + rr;
    out[(size_t)grow * 64 + c] = acc * dinv[grow];
  }
}

// ---------------------------------------------------------------- edge scatter
// agg[dst, lane] += g[src, lane]   (one wave per edge; 64 lanes = 64 features)
__global__ __launch_bounds__(256) void scatter_add_kernel(const int* __restrict__ src,
                                                          const int* __restrict__ dst,
                                                          const float* __restrict__ g,
                                                          float* __restrict__ agg, int E) {
  const int lane = threadIdx.x & 63;
  int w = (blockIdx.x * 256 + threadIdx.x) >> 6;
  const int nw = (gridDim.x * 256) >> 6;
  for (; w < E; w += nw) {
    const int s = src[w];                      // lane-uniform -> L1 broadcast
    const int d = dst[w];
    const float v = g[(size_t)s * 64 + lane];  // coalesced 256B row gather
    unsafeAtomicAdd(&agg[(size_t)d * 64 + lane], v);  // native global_atomic_add_f32
  }
}

// ---------------------------------------------------------------- epilogue per layer
// agg[i,c] = relu( (agg[i,c] + g[i,c]) * dinv[i] + b[c] )    (g term = self-loop)
__global__ __launch_bounds__(256) void finalize_kernel(float* agg,
                                                       const float* __restrict__ g,
                                                       const float* __restrict__ dinv,
                                                       const float* __restrict__ b) {
  const int i = blockIdx.x * 256 + threadIdx.x;  // float4 index, N*16 total
  const int row = i >> 4, cq = (i & 15) * 4;
  const float di = dinv[row];
  float4 a = reinterpret_cast<float4*>(agg)[i];
  const float4 gv = reinterpret_cast<const float4*>(g)[i];
  a.x = fmaxf(fmaf(a.x + gv.x, di, b[cq + 0]), 0.f);
  a.y = fmaxf(fmaf(a.y + gv.y, di, b[cq + 1]), 0.f);
  a.z = fmaxf(fmaf(a.z + gv.z, di, b[cq + 2]), 0.f);
  a.w = fmaxf(fmaf(a.w + gv.w, di, b[cq + 3]), 0.f);
  reinterpret_cast<float4*>(agg)[i] = a;
}

// ---------------------------------------------------------------- final FC (64 -> 11)
__global__ __launch_bounds__(256) void gemm_fc(const float* __restrict__ h,
                                               const float* __restrict__ W,
                                               const float* __restrict__ b,
                                               float* __restrict__ out) {
  __shared__ float Wl[772];     // [k][12] padded (zero-filled; lanes c=11..15 read junk-safe zeros)
  __shared__ float xl[16][68];  // 68-stride: conflict-free 4-distinct-row reads
  const int tid = threadIdx.x;
  for (int i = tid; i < 772; i += 256) Wl[i] = 0.f;
  __syncthreads();
  for (int i = tid; i < 64 * 11; i += 256) Wl[(i / 11) * 12 + (i % 11)] = W[i];
  const int row0 = blockIdx.x * 16;
  for (int i = tid; i < 16 * 16; i += 256) {  // 16 rows x 16 float4
    const int r = i >> 4, q = i & 15;
    const float4 v = reinterpret_cast<const float4*>(h + (size_t)(row0 + r) * 64)[q];
    xl[r][q * 4 + 0] = v.x; xl[r][q * 4 + 1] = v.y;
    xl[r][q * 4 + 2] = v.z; xl[r][q * 4 + 3] = v.w;
  }
  __syncthreads();
  const int r = tid >> 4, c = tid & 15;
  float acc = 0.f;
#pragma unroll
  for (int k = 0; k < 64; k += 4) {
    acc = fmaf(xl[r][k + 0], Wl[(k + 0) * 12 + c], acc);
    acc = fmaf(xl[r][k + 1], Wl[(k + 1) * 12 + c], acc);
    acc = fmaf(xl[r][k + 2], Wl[(k + 2) * 12 + c], acc);
    acc = fmaf(xl[r][k + 3], Wl[(k + 3) * 12 + c], acc);
  }
  if (c < 11) out[(size_t)(row0 + r) * 11 + c] = acc + b[c];
}

// ---------------------------------------------------------------- launch
extern "C" void kernel_launch(void* const* d_in, const int* in_sizes, int n_in,
                              void* d_out, int out_size, void* d_ws, size_t ws_size,
                              hipStream_t stream) {
  const float* x   = (const float*)d_in[0];
  const int*   ei  = (const int*)d_in[1];   // [2, E] int32 (jax x64 disabled)
  const float* W1  = (const float*)d_in[2];
  const float* b1  = (const float*)d_in[3];
  const float* W2  = (const float*)d_in[4];
  const float* b2  = (const float*)d_in[5];
  const float* Wfc = (const float*)d_in[6];
  const float* bfc = (const float*)d_in[7];
  float* out = (float*)d_out;

  const int n = in_sizes[0] / 128;  // 100000
  const int E = in_sizes[1] / 2;    // 3200000
  const int* src = ei;
  const int* dst = ei + E;

  char* ws = (char*)d_ws;
  size_t o = 0;
  auto alloc = [&](size_t bytes) {
    char* p = ws + o;
    o += (bytes + 255) & ~(size_t)255;
    return p;
  };
  int*   deg  = (int*)  alloc((size_t)n * 4);
  float* dinv = (float*)alloc((size_t)n * 4);
  float* B0   = (float*)alloc((size_t)n * HID * 4);  // g = dinv * (x@W)
  float* B1   = (float*)alloc((size_t)n * HID * 4);  // agg / layer output
  if (o > ws_size) return;  // workspace too small: fail loud, not corrupt

  const int gblocks = n / 16;  // 6250, exact

  hipMemsetAsync(deg, 0, (size_t)n * 4, stream);
  count_deg<<<2048, 256, 0, stream>>>(dst, deg, E);
  compute_dinv<<<(n + 255) / 256, 256, 0, stream>>>(deg, dinv, n);

  // ---- layer 1
  gemm_nodes<128><<<gblocks, 256, 0, stream>>>(x, W1, dinv, B0);
  hipMemsetAsync(B1, 0, (size_t)n * HID * 4, stream);
  scatter_add_kernel<<<8192, 256, 0, stream>>>(src, dst, B0, B1, E);
  finalize_kernel<<<gblocks, 256, 0, stream>>>(B1, B0, dinv, b1);

  // ---- layer 2
  gemm_nodes<64><<<gblocks, 256, 0, stream>>>(B1, W2, dinv, B0);
  hipMemsetAsync(B1, 0, (size_t)n * HID * 4, stream);
  scatter_add_kernel<<<8192, 256, 0, stream>>>(src, dst, B0, B1, E);
  finalize_kernel<<<gblocks, 256, 0, stream>>>(B1, B0, dinv, b2);

  // ---- FC head
  gemm_fc<<<gblocks, 256, 0, stream>>>(B1, Wfc, bfc, out);
}

// Round 2
// 753.202 us; speedup vs baseline: 2.1138x; 2.1138x over previous
//
#include <hip/hip_runtime.h>

#define HID 64

// ---------------------------------------------------------------- degree
__global__ __launch_bounds__(256) void count_deg(const int* __restrict__ dst,
                                                 int* __restrict__ deg, int E) {
  int i = blockIdx.x * 256 + threadIdx.x;
  const int stride = gridDim.x * 256;
  for (; i < E; i += stride) atomicAdd(&deg[dst[i]], 1);
}

__global__ __launch_bounds__(256) void compute_dinv(const int* __restrict__ deg,
                                                    float* __restrict__ dinv, int n) {
  const int i = blockIdx.x * 256 + threadIdx.x;
  if (i < n) dinv[i] = rsqrtf((float)(deg[i] + 1));  // +1 self-loop
}

// ---------------------------------------------------------------- CSR build: scan
__global__ __launch_bounds__(256) void scan_blocks(const int* __restrict__ deg,
                                                   int* __restrict__ rowptr,
                                                   int* __restrict__ bsum, int n) {
  __shared__ int s[256];
  const int t = threadIdx.x;
  const int i = blockIdx.x * 256 + t;
  const int v = (i < n) ? deg[i] : 0;
  s[t] = v;
  __syncthreads();
  for (int off = 1; off < 256; off <<= 1) {
    const int u = (t >= off) ? s[t - off] : 0;
    __syncthreads();
    s[t] += u;
    __syncthreads();
  }
  if (i < n) rowptr[i] = s[t] - v;          // block-local exclusive
  if (t == 255) bsum[blockIdx.x] = s[255];  // block total
}

__global__ __launch_bounds__(512) void scan_top(int* bsum, int nb) {
  __shared__ int s[512];
  const int t = threadIdx.x;
  const int v = (t < nb) ? bsum[t] : 0;
  s[t] = v;
  __syncthreads();
  for (int off = 1; off < 512; off <<= 1) {
    const int u = (t >= off) ? s[t - off] : 0;
    __syncthreads();
    s[t] += u;
    __syncthreads();
  }
  if (t < nb) bsum[t] = s[t] - v;  // exclusive block offsets
}

__global__ __launch_bounds__(256) void add_offsets(int* __restrict__ rowptr,
                                                   const int* __restrict__ bsum,
                                                   int n, int E) {
  const int i = blockIdx.x * 256 + threadIdx.x;
  if (i < n) rowptr[i] += bsum[blockIdx.x];
  if (i == 0) rowptr[n] = E;
}

// ---------------------------------------------------------------- CSR fill
__global__ __launch_bounds__(256) void fill_csr(const int* __restrict__ src,
                                                const int* __restrict__ dst,
                                                int* __restrict__ cursor,
                                                int* __restrict__ colidx, int E) {
  int i = blockIdx.x * 256 + threadIdx.x;
  const int stride = gridDim.x * 256;
  for (; i < E; i += stride) {
    const int p = atomicAdd(&cursor[dst[i]], 1);
    colidx[p] = src[i];
  }
}

// ---------------------------------------------------------------- dense transform
// out[i, c] = dinv[i] * sum_k x[i,k] * W[k,c]      (16 rows/block, 64 cols)
template <int K>
__global__ __launch_bounds__(256) void gemm_nodes(const float* __restrict__ x,
                                                  const float* __restrict__ W,
                                                  const float* __restrict__ dinv,
                                                  float* __restrict__ out) {
  __shared__ float Wl[K * 64];
  __shared__ float xl[16][K];
  const int tid = threadIdx.x;
  for (int i = tid; i < K * 16; i += 256)
    reinterpret_cast<float4*>(Wl)[i] = reinterpret_cast<const float4*>(W)[i];
  const int row0 = blockIdx.x * 16;
  for (int i = tid; i < 16 * (K / 4); i += 256) {
    const int r = i / (K / 4), q = i % (K / 4);
    reinterpret_cast<float4*>(&xl[r][0])[q] =
        reinterpret_cast<const float4*>(x + (size_t)(row0 + r) * K)[q];
  }
  __syncthreads();
  const int c = tid & 63;
  const int rbase = tid >> 6;
  for (int rr = rbase; rr < 16; rr += 4) {
    float acc = 0.f;
#pragma unroll
    for (int k = 0; k < K; k += 4) {
      const float4 xv = *reinterpret_cast<const float4*>(&xl[rr][k]);
      acc = fmaf(xv.x, Wl[(k + 0) * 64 + c], acc);
      acc = fmaf(xv.y, Wl[(k + 1) * 64 + c], acc);
      acc = fmaf(xv.z, Wl[(k + 2) * 64 + c], acc);
      acc = fmaf(xv.w, Wl[(k + 3) * 64 + c], acc);
    }
    const int grow = row0 + rr;
    out[(size_t)grow * 64 + c] = acc * dinv[grow];
  }
}

// ---------------------------------------------------------------- pull aggregation
// out[d,lane] = relu( dinv[d] * (sum_{s in N(d)} g[s,lane] + g[d,lane]) + b[lane] )
// one wave per node; g rows already pre-scaled by dinv[src]
__global__ __launch_bounds__(256) void gather_agg(const int* __restrict__ rowptr,
                                                  const int* __restrict__ colidx,
                                                  const float* __restrict__ g,
                                                  const float* __restrict__ dinv,
                                                  const float* __restrict__ b,
                                                  float* __restrict__ out, int n) {
  const int lane = threadIdx.x & 63;
  const int node = (blockIdx.x * 256 + threadIdx.x) >> 6;
  if (node >= n) return;
  const int beg = rowptr[node];
  const int end = rowptr[node + 1];
  float acc = 0.f;
  int e = beg;
  for (; e + 4 <= end; e += 4) {  // 4-deep ILP to hide gather latency
    const int s0 = colidx[e + 0], s1 = colidx[e + 1];
    const int s2 = colidx[e + 2], s3 = colidx[e + 3];
    const float v0 = g[(size_t)s0 * HID + lane];
    const float v1 = g[(size_t)s1 * HID + lane];
    const float v2 = g[(size_t)s2 * HID + lane];
    const float v3 = g[(size_t)s3 * HID + lane];
    acc += (v0 + v1) + (v2 + v3);
  }
  for (; e < end; ++e) acc += g[(size_t)colidx[e] * HID + lane];
  acc += g[(size_t)node * HID + lane];  // self-loop (dinv[node]-scaled already)
  const float r = fmaf(acc, dinv[node], b[lane]);
  out[(size_t)node * HID + lane] = fmaxf(r, 0.f);
}

// ---------------------------------------------------------------- final FC (64 -> 11)
__global__ __launch_bounds__(256) void gemm_fc(const float* __restrict__ h,
                                               const float* __restrict__ W,
                                               const float* __restrict__ b,
                                               float* __restrict__ out) {
  __shared__ float Wl[772];     // [k][12] padded, zero-filled
  __shared__ float xl[16][68];  // padded stride
  const int tid = threadIdx.x;
  for (int i = tid; i < 772; i += 256) Wl[i] = 0.f;
  __syncthreads();
  for (int i = tid; i < 64 * 11; i += 256) Wl[(i / 11) * 12 + (i % 11)] = W[i];
  const int row0 = blockIdx.x * 16;
  for (int i = tid; i < 16 * 16; i += 256) {
    const int r = i >> 4, q = i & 15;
    const float4 v = reinterpret_cast<const float4*>(h + (size_t)(row0 + r) * 64)[q];
    xl[r][q * 4 + 0] = v.x; xl[r][q * 4 + 1] = v.y;
    xl[r][q * 4 + 2] = v.z; xl[r][q * 4 + 3] = v.w;
  }
  __syncthreads();
  const int r = tid >> 4, c = tid & 15;
  float acc = 0.f;
#pragma unroll
  for (int k = 0; k < 64; k += 4) {
    acc = fmaf(xl[r][k + 0], Wl[(k + 0) * 12 + c], acc);
    acc = fmaf(xl[r][k + 1], Wl[(k + 1) * 12 + c], acc);
    acc = fmaf(xl[r][k + 2], Wl[(k + 2) * 12 + c], acc);
    acc = fmaf(xl[r][k + 3], Wl[(k + 3) * 12 + c], acc);
  }
  if (c < 11) out[(size_t)(row0 + r) * 11 + c] = acc + b[c];
}

// ---------------------------------------------------------------- launch
extern "C" void kernel_launch(void* const* d_in, const int* in_sizes, int n_in,
                              void* d_out, int out_size, void* d_ws, size_t ws_size,
                              hipStream_t stream) {
  const float* x   = (const float*)d_in[0];
  const int*   ei  = (const int*)d_in[1];   // [2, E] int32
  const float* W1  = (const float*)d_in[2];
  const float* b1  = (const float*)d_in[3];
  const float* W2  = (const float*)d_in[4];
  const float* b2  = (const float*)d_in[5];
  const float* Wfc = (const float*)d_in[6];
  const float* bfc = (const float*)d_in[7];
  float* out = (float*)d_out;

  const int n = in_sizes[0] / 128;  // 100000
  const int E = in_sizes[1] / 2;    // 3200000
  const int* src = ei;
  const int* dst = ei + E;

  char* ws = (char*)d_ws;
  size_t o = 0;
  auto alloc = [&](size_t bytes) {
    char* p = ws + o;
    o += (bytes + 255) & ~(size_t)255;
    return p;
  };
  int*   deg    = (int*)  alloc((size_t)n * 4);
  float* dinv   = (float*)alloc((size_t)n * 4);
  int*   rowptr = (int*)  alloc((size_t)(n + 1) * 4);
  int*   cursor = (int*)  alloc((size_t)n * 4);
  int*   bsum   = (int*)  alloc(512 * 4);
  int*   colidx = (int*)  alloc((size_t)E * 4);
  float* B0     = (float*)alloc((size_t)n * HID * 4);  // g = dinv * (x@W)
  float* B1     = (float*)alloc((size_t)n * HID * 4);  // layer output
  if (o > ws_size) return;

  const int nb = (n + 255) / 256;  // 391 scan blocks
  const int gblocks = n / 16;      // 6250 gemm blocks

  // ---- graph preprocessing (shared by both layers)
  hipMemsetAsync(deg, 0, (size_t)n * 4, stream);
  count_deg<<<2048, 256, 0, stream>>>(dst, deg, E);
  compute_dinv<<<nb, 256, 0, stream>>>(deg, dinv, n);
  scan_blocks<<<nb, 256, 0, stream>>>(deg, rowptr, bsum, n);
  scan_top<<<1, 512, 0, stream>>>(bsum, nb);
  add_offsets<<<nb, 256, 0, stream>>>(rowptr, bsum, n, E);
  hipMemcpyAsync(cursor, rowptr, (size_t)n * 4, hipMemcpyDeviceToDevice, stream);
  fill_csr<<<4096, 256, 0, stream>>>(src, dst, cursor, colidx, E);

  const int pull_blocks = (n * 64 + 255) / 256;  // one wave per node

  // ---- layer 1
  gemm_nodes<128><<<gblocks, 256, 0, stream>>>(x, W1, dinv, B0);
  gather_agg<<<pull_blocks, 256, 0, stream>>>(rowptr, colidx, B0, dinv, b1, B1, n);

  // ---- layer 2
  gemm_nodes<64><<<gblocks, 256, 0, stream>>>(B1, W2, dinv, B0);
  gather_agg<<<pull_blocks, 256, 0, stream>>>(rowptr, colidx, B0, dinv, b2, B1, n);

  // ---- FC head
  gemm_fc<<<gblocks, 256, 0, stream>>>(B1, Wfc, bfc, out);
}